// Round 7
// baseline (607.173 us; speedup 1.0000x reference)
//
#include <hip/hip_runtime.h>
#include <stdint.h>

#define NN 32768
#define DEG 16
#define CH 128
#define MB 128         // nodes per LSTM block (two 64-node halves)
#define BUF 32768      // byte stride between the two h buffers (128 rows x 256B)

typedef short bf16x8 __attribute__((ext_vector_type(8)));
typedef float f32x4 __attribute__((ext_vector_type(4)));
typedef unsigned short u16;
typedef u16 u16x8 __attribute__((ext_vector_type(8)));
typedef uint32_t u32;

#define L2E  1.4426950408889634f
#define L2E2 2.8853900817779268f

__device__ __forceinline__ u16 f2bf(float f) {
  union { float f; uint32_t u; } v; v.f = f;
  uint32_t u = v.u;
  return (u16)((u + 0x7FFFu + ((u >> 16) & 1u)) >> 16);
}
// trans ops via builtins: compiler inserts the trans->VALU wait state.
__device__ __forceinline__ float exp2f_fast(float x) {
#if __has_builtin(__builtin_amdgcn_exp2f)
  return __builtin_amdgcn_exp2f(x);
#else
  float r; asm volatile("v_exp_f32 %0, %1\n\ts_nop 0" : "=v"(r) : "v"(x)); return r;
#endif
}
__device__ __forceinline__ float rcpf_fast(float x) {
#if __has_builtin(__builtin_amdgcn_rcpf)
  return __builtin_amdgcn_rcpf(x);
#else
  float r; asm volatile("v_rcp_f32 %0, %1\n\ts_nop 0" : "=v"(r) : "v"(x)); return r;
#endif
}
__device__ __forceinline__ u32 cvtpk(float lo, float hi) {
  u32 r; asm("v_cvt_pk_bf16_f32 %0, %1, %2" : "=v"(r) : "v"(lo), "v"(hi));
  return r;
}

// ---------------- merged prep (1 launch) ----------------
__global__ void k_prep(const float* __restrict__ x, u16* __restrict__ x_bf,
    const float* __restrict__ w1ih, const float* __restrict__ w1hh,
    const float* __restrict__ b1ih, const float* __restrict__ b1hh,
    u16* __restrict__ Wc1, float* __restrict__ bs1,
    const float* __restrict__ w2ih, const float* __restrict__ w2hh,
    const float* __restrict__ b2ih, const float* __restrict__ b2hh,
    u16* __restrict__ Wc2, float* __restrict__ bs2,
    const float* __restrict__ w1l, const float* __restrict__ w1r, u16* __restrict__ Wl1,
    const float* __restrict__ w2l, const float* __restrict__ w2r, u16* __restrict__ Wl2) {
  const int bid = blockIdx.x, tid = threadIdx.x;
  { // x -> bf16 (2048*256 chunks of 8)
    int i = bid * 256 + tid;
    const float* pp = x + (size_t)i * 8;
    u16x8 o;
    #pragma unroll
    for (int j = 0; j < 8; ++j) o[j] = f2bf(pp[j]);
    *(u16x8*)(x_bf + (size_t)i * 8) = o;
  }
  if (bid < 1024) {            // LSTM weight packs (pre-scaled by log2e / 2log2e)
    const int b2 = bid >= 512;
    const float* wih = b2 ? w2ih : w1ih;
    const float* whh = b2 ? w2hh : w1hh;
    const float* bih = b2 ? b2ih : b1ih;
    const float* bhh = b2 ? b2hh : b1hh;
    u16* Wc = b2 ? Wc2 : Wc1;
    float* bsp = b2 ? bs2 : bs1;
    int idx = (bid & 511) * 256 + tid;
    int g = idx >> 8, k = idx & 255;
    float sc = ((g >> 7) == 2) ? L2E2 : L2E;
    float v = (k < CH) ? wih[g * CH + k] : whh[g * CH + (k - CH)];
    Wc[g * 256 + k] = f2bf(v * sc);
    if (k == 0) bsp[g] = (bih[g] + bhh[g]) * sc;
  } else if (bid < 1280) {     // linear packs
    const int b2 = bid >= 1152;
    const float* wl = b2 ? w2l : w1l;
    const float* wr = b2 ? w2r : w1r;
    u16* W = b2 ? Wl2 : Wl1;
    int idx = ((bid - 1024) & 127) * 256 + tid;
    int o = idx >> 8, k = idx & 255;
    float v = (k < CH) ? wl[o * CH + k] : wr[o * CH + (k - CH)];
    W[o * 256 + k] = f2bf(v);
  }
}

// ---------------- Gx = x @ wih.T + b (pre-scaled), [node][c][gate] bf16 ----------------
__global__ __launch_bounds__(512, 2)
void k_gates(const u16* __restrict__ xin, const u16* __restrict__ Wc,
             const float* __restrict__ bs, u16* __restrict__ gx) {
  const int lane = threadIdx.x & 63;
  const int wave = threadIdx.x >> 6;
  const int l15 = lane & 15, lg = lane >> 4;
  const int nodeBase = blockIdx.x * 64;

  bf16x8 B[4][4];
  float bv[4];
  int cb[4];
  #pragma unroll
  for (int ct = 0; ct < 4; ++ct) {
    int j = (wave * 4 + ct) * 16 + l15;
    int wr = ((j & 3) << 7) + (j >> 2);
    cb[ct] = (j >> 2) * 8 + (j & 3) * 2;
    bv[ct] = bs[wr];
    #pragma unroll
    for (int kt = 0; kt < 4; ++kt)
      B[ct][kt] = *(const bf16x8*)(Wc + wr * 256 + kt * 32 + lg * 8);
  }
  char* gxc = (char*)gx;
  #pragma unroll
  for (int mt = 0; mt < 4; ++mt) {
    bf16x8 A[4];
    #pragma unroll
    for (int kt = 0; kt < 4; ++kt)
      A[kt] = *(const bf16x8*)(xin + (size_t)(nodeBase + mt * 16 + l15) * CH + kt * 32 + lg * 8);
    f32x4 acc[4];
    #pragma unroll
    for (int ct = 0; ct < 4; ++ct) acc[ct] = { bv[ct], bv[ct], bv[ct], bv[ct] };
    #pragma unroll
    for (int kt = 0; kt < 4; ++kt)
      #pragma unroll
      for (int ct = 0; ct < 4; ++ct)
        acc[ct] = __builtin_amdgcn_mfma_f32_16x16x32_bf16(A[kt], B[ct][kt], acc[ct], 0, 0, 0);
    #pragma unroll
    for (int ct = 0; ct < 4; ++ct)
      #pragma unroll
      for (int q = 0; q < 4; ++q)
        *(u16*)(gxc + (size_t)(nodeBase + mt * 16 + lg * 4 + q) * 1024 + cb[ct]) =
            f2bf(acc[ct][q]);
  }
}

// ---------------- LSTM recurrence (h @ whh.T; x-part gathered from Gx) ----------------
// ONE 1024-thread block per CU (grid 256): 16 waves = 4/SIMD occupancy AND
// whole-machine step-sync (each XCD's per-step gather set ~4MB fits its L2).
// Wave w: channel group w&7, node half w>>3. Per-wave code identical to r6.
#define GXLD(SET, TOFF, M) do {                                                \
    int4 sv_ = *(const int4*)(ldsc + sTr + ((TOFF) * 512 + (M) * 64));         \
    SET[0] = *(const uint2*)(gxp + ((size_t)(u32)sv_.x << 10));                \
    SET[1] = *(const uint2*)(gxp + ((size_t)(u32)sv_.y << 10));                \
    SET[2] = *(const uint2*)(gxp + ((size_t)(u32)sv_.z << 10));                \
    SET[3] = *(const uint2*)(gxp + ((size_t)(u32)sv_.w << 10));                \
  } while (0)

#define MT_BODY(MT, G, ISSUE_STMT) do {                                        \
  ISSUE_STMT;                                                                  \
  f32x4 acg[4];                                                                \
  _Pragma("unroll")                                                            \
  for (int q = 0; q < 4; ++q) {                                                \
    acg[0][q] = __uint_as_float((u32)G[q].x << 16);                            \
    acg[1][q] = __uint_as_float(G[q].x & 0xFFFF0000u);                         \
    acg[2][q] = __uint_as_float((u32)G[q].y << 16);                            \
    acg[3][q] = __uint_as_float(G[q].y & 0xFFFF0000u);                         \
  }                                                                            \
  bf16x8 Aa[4];                                                                \
  Aa[0] = *(const bf16x8*)(ldsc + aAr + (MT) * 4096);                          \
  Aa[1] = *(const bf16x8*)(ldsc + aBr + (MT) * 4096);                          \
  Aa[2] = *(const bf16x8*)(ldsc + aAr + (MT) * 4096 + 128);                    \
  Aa[3] = *(const bf16x8*)(ldsc + aBr + (MT) * 4096 + 128);                    \
  __builtin_amdgcn_s_setprio(1);                                               \
  _Pragma("unroll")                                                            \
  for (int kt = 0; kt < 4; ++kt)                                               \
    _Pragma("unroll")                                                          \
    for (int gt = 0; gt < 4; ++gt)                                             \
      acg[gt] = __builtin_amdgcn_mfma_f32_16x16x32_bf16(Aa[kt], Wf[gt][kt],    \
                                                        acg[gt], 0, 0, 0);     \
  __builtin_amdgcn_s_setprio(0);                                               \
  float hq[4];                                                                 \
  _Pragma("unroll")                                                            \
  for (int q = 0; q < 4; ++q) {                                                \
    float si = rcpf_fast(1.0f + exp2f_fast(-acg[0][q]));                       \
    float sf = rcpf_fast(1.0f + exp2f_fast(-acg[1][q]));                       \
    float so = rcpf_fast(1.0f + exp2f_fast(-acg[3][q]));                       \
    float gg = fmaf(-2.0f, rcpf_fast(1.0f + exp2f_fast(acg[2][q])), 1.0f);     \
    float c  = fmaf(sf, cst[MT][q], si * gg);                                  \
    cst[MT][q] = c;                                                            \
    float tc = fmaf(-2.0f, rcpf_fast(1.0f + exp2f_fast(c * L2E2)), 1.0f);      \
    hq[q] = so * tc;                                                           \
  }                                                                            \
  u32 hp0 = cvtpk(hq[0], hq[1]);                                               \
  u32 hp1 = cvtpk(hq[2], hq[3]);                                               \
  if (t != DEG - 1) {                                                          \
    *(u16*)(ldsc + (hwB ^  0) + (MT) * 4096 +   0) = (u16)hp0;                 \
    *(u16*)(ldsc + (hwB ^ 16) + (MT) * 4096 + 256) = (u16)(hp0 >> 16);         \
    *(u16*)(ldsc + (hwB ^ 32) + (MT) * 4096 + 512) = (u16)hp1;                 \
    *(u16*)(ldsc + (hwB ^ 48) + (MT) * 4096 + 768) = (u16)(hp1 >> 16);         \
  } else {                                                                     \
    u16* op_ = aggr + (size_t)(nodeBase + wh * 64 + (MT) * 16 + lg * 4) * CH   \
               + w8 * 16 + l15;                                                \
    op_[0 * CH] = (u16)hp0;                                                    \
    op_[1 * CH] = (u16)(hp0 >> 16);                                            \
    op_[2 * CH] = (u16)hp1;                                                    \
    op_[3 * CH] = (u16)(hp1 >> 16);                                            \
  }                                                                            \
} while (0)

__global__ __launch_bounds__(1024, 4)
void k_lstm(const u16* __restrict__ gx, const int* __restrict__ src,
            const u16* __restrict__ Wc, u16* __restrict__ aggr) {
  __shared__ char ldsA[2 * BUF + 8192];   // h dbuf (swizzled) + srcsT[t][128]
  char* ldsc = ldsA;
  const int tid = threadIdx.x;
  const int lane = tid & 63;
  const int wave = tid >> 6;
  const int w8  = wave & 7;          // channel group
  const int wh  = wave >> 3;         // node half
  const int l15 = lane & 15;
  const int lg  = lane >> 4;
  const int nodeBase = blockIdx.x * MB;

  { // stage srcsT[t][node] (transposed): 128 nodes x 16 t
    int row = tid >> 3, tq = (tid & 7) * 2;
    int2 s2 = *(const int2*)(src + (size_t)(nodeBase + row) * DEG + tq);
    *(int*)(ldsc + 2 * BUF + tq * 512 + row * 4)       = s2.x;
    *(int*)(ldsc + 2 * BUF + (tq + 1) * 512 + row * 4) = s2.y;
  }
  { // zero h buffer 0 (32KB)
    int4 z = {0, 0, 0, 0};
    *(int4*)(ldsc + tid * 32)      = z;
    *(int4*)(ldsc + tid * 32 + 16) = z;
  }

  // whh B-frags (pre-scaled): row = gate*128 + w8*16 + l15, k in [128,256)
  bf16x8 Wf[4][4];
  {
    const u16* wp = Wc + (w8 * 16 + l15) * 256 + 128 + lg * 8;
    #pragma unroll
    for (int gt = 0; gt < 4; ++gt)
      #pragma unroll
      for (int kt = 0; kt < 4; ++kt)
        Wf[gt][kt] = *(const bf16x8*)(wp + gt * (CH * 256) + kt * 32);
  }

  // hoisted addresses (row stride 256B; swizzle: byte col ^= (row&7)<<4)
  int aAr = wh * 16384 + l15 * 256 + ((lg * 16) ^ ((l15 & 7) << 4));
  int aBr = aAr ^ 64;
  int hwB = wh * 16384 + lg * 1024 + (((w8 * 16 + l15) * 2) ^ ((lg & 1) << 6)) + BUF;
  int sTr = 2 * BUF + wh * 256 + lg * 16;       // srcsT base, += 512 per step
  const char* gxp = (const char*)gx + (size_t)(w8 * 16 + l15) * 8;

  float cst[4][4] = {{0.f}};

  __syncthreads();                  // srcsT + zeroed h visible
  uint2 gq0[4], gq1[4], gq2[4], gq3[4];
  GXLD(gq0, 0, 0);

  #pragma unroll 1
  for (int t = 0; t < DEG; ++t) {
    GXLD(gq1, 0, 1);
    MT_BODY(0, gq0, GXLD(gq2, 0, 2));
    MT_BODY(1, gq1, GXLD(gq3, 0, 3));
    MT_BODY(2, gq2, if (t != DEG - 1) GXLD(gq0, 1, 0));
    MT_BODY(3, gq3, );
    aAr ^= BUF; aBr ^= BUF; hwB ^= BUF;
    sTr += 512;
    __syncthreads();                // h(t) visible; old buffer free
  }
}

// ---------------- fused lin_l/lin_r ----------------
__global__ __launch_bounds__(256, 4)
void k_linear(const u16* __restrict__ aggr, const u16* __restrict__ xroot,
              const u16* __restrict__ W, const float* __restrict__ bl,
              u16* __restrict__ out_bf, float* __restrict__ out_f, int relu) {
  const int lane = threadIdx.x & 63;
  const int wave = threadIdx.x >> 6;
  const int l15 = lane & 15, lg = lane >> 4;
  const int rowBase = blockIdx.x * 64 + wave * 16;

  f32x4 acc[8];
  #pragma unroll
  for (int nt = 0; nt < 8; ++nt) {
    float b = bl[nt * 16 + l15];
    acc[nt] = { b, b, b, b };
  }
  #pragma unroll
  for (int kt = 0; kt < 8; ++kt) {
    const u16* ap = (kt < 4) ? (aggr  + (size_t)(rowBase + l15) * CH + kt * 32 + lg * 8)
                             : (xroot + (size_t)(rowBase + l15) * CH + (kt - 4) * 32 + lg * 8);
    bf16x8 A = *(const bf16x8*)ap;
    #pragma unroll
    for (int nt = 0; nt < 8; ++nt) {
      bf16x8 B = *(const bf16x8*)(W + (nt * 16 + l15) * 256 + kt * 32 + lg * 8);
      acc[nt] = __builtin_amdgcn_mfma_f32_16x16x32_bf16(A, B, acc[nt], 0, 0, 0);
    }
  }
  #pragma unroll
  for (int nt = 0; nt < 8; ++nt) {
    #pragma unroll
    for (int q = 0; q < 4; ++q) {
      float v = acc[nt][q];
      if (relu) v = fmaxf(v, 0.0f);
      int row = rowBase + lg * 4 + q;
      int col = nt * 16 + l15;
      if (out_bf) out_bf[(size_t)row * CH + col] = f2bf(v);
      else        out_f[(size_t)row * CH + col]  = v;
    }
  }
}

extern "C" void kernel_launch(void* const* d_in, const int* in_sizes, int n_in,
                              void* d_out, int out_size, void* d_ws, size_t ws_size,
                              hipStream_t stream) {
  (void)in_sizes; (void)n_in; (void)out_size; (void)ws_size;
  const float* x    = (const float*)d_in[0];
  const int*   ei   = (const int*)d_in[1];
  const float* w1ih = (const float*)d_in[2];
  const float* w1hh = (const float*)d_in[3];
  const float* b1ih = (const float*)d_in[4];
  const float* b1hh = (const float*)d_in[5];
  const float* w1l  = (const float*)d_in[6];
  const float* b1l  = (const float*)d_in[7];
  const float* w1r  = (const float*)d_in[8];
  const float* w2ih = (const float*)d_in[9];
  const float* w2hh = (const float*)d_in[10];
  const float* b2ih = (const float*)d_in[11];
  const float* b2hh = (const float*)d_in[12];
  const float* w2l  = (const float*)d_in[13];
  const float* b2l  = (const float*)d_in[14];
  const float* w2r  = (const float*)d_in[15];

  char* p = (char*)d_ws;
  u16* x_bf  = (u16*)p;  p += (size_t)NN * CH * 2;
  u16* h1_bf = (u16*)p;  p += (size_t)NN * CH * 2;
  u16* ag_bf = (u16*)p;  p += (size_t)NN * CH * 2;
  u16* Wc1   = (u16*)p;  p += (size_t)512 * 256 * 2;
  u16* Wc2   = (u16*)p;  p += (size_t)512 * 256 * 2;
  u16* Wl1   = (u16*)p;  p += (size_t)CH * 256 * 2;
  u16* Wl2   = (u16*)p;  p += (size_t)CH * 256 * 2;
  float* bs1 = (float*)p; p += 512 * 4;
  float* bs2 = (float*)p; p += 512 * 4;
  u16* Gx    = (u16*)p;  p += (size_t)NN * 512 * 2;   // 32 MB

  k_prep<<<2048, 256, 0, stream>>>(x, x_bf,
      w1ih, w1hh, b1ih, b1hh, Wc1, bs1,
      w2ih, w2hh, b2ih, b2hh, Wc2, bs2,
      w1l, w1r, Wl1, w2l, w2r, Wl2);

  k_gates<<<NN / 64, 512, 0, stream>>>(x_bf, Wc1, bs1, Gx);
  k_lstm<<<NN / MB, 1024, 0, stream>>>(Gx, ei, Wc1, ag_bf);
  k_linear<<<NN / 64, 256, 0, stream>>>(ag_bf, x_bf, Wl1, b1l, h1_bf, nullptr, 1);
  k_gates<<<NN / 64, 512, 0, stream>>>(h1_bf, Wc2, bs2, Gx);
  k_lstm<<<NN / MB, 1024, 0, stream>>>(Gx, ei, Wc2, ag_bf);
  k_linear<<<NN / 64, 256, 0, stream>>>(ag_bf, h1_bf, Wl2, b2l, nullptr, (float*)d_out, 0);
}

// Round 10
// 569.239 us; speedup vs baseline: 1.0666x; 1.0666x over previous
//
#include <hip/hip_runtime.h>
#include <stdint.h>

#define NN 32768
#define DEG 16
#define CH 128
#define MB 64

typedef short bf16x8 __attribute__((ext_vector_type(8)));
typedef float f32x4 __attribute__((ext_vector_type(4)));
typedef unsigned short u16;
typedef u16 u16x8 __attribute__((ext_vector_type(8)));
typedef uint32_t u32;

#define L2E  1.4426950408889634f
#define L2E2 2.8853900817779268f

// LDS map (bytes)
#define EXB  65536    // exch: [8 g][4 mt][TG 1024 | SO 1024]      = 65536
#define STB  131072   // srcsT [16 t][64 node] x int               = 4096
#define LDSZ 135168   // xh dbuf [2][64 rows][512B [x|h]] at 0     = 65536

__device__ __forceinline__ u16 f2bf(float f) {
  union { float f; uint32_t u; } v; v.f = f;
  uint32_t u = v.u;
  return (u16)((u + 0x7FFFu + ((u >> 16) & 1u)) >> 16);
}
__device__ __forceinline__ float exp2f_fast(float x) {
#if __has_builtin(__builtin_amdgcn_exp2f)
  return __builtin_amdgcn_exp2f(x);
#else
  float r; asm volatile("v_exp_f32 %0, %1\n\ts_nop 0" : "=v"(r) : "v"(x)); return r;
#endif
}
__device__ __forceinline__ float rcpf_fast(float x) {
#if __has_builtin(__builtin_amdgcn_rcpf)
  return __builtin_amdgcn_rcpf(x);
#else
  float r; asm volatile("v_rcp_f32 %0, %1\n\ts_nop 0" : "=v"(r) : "v"(x)); return r;
#endif
}
__device__ __forceinline__ u32 cvtpk(float lo, float hi) {
  u32 r; asm("v_cvt_pk_bf16_f32 %0, %1, %2" : "=v"(r) : "v"(lo), "v"(hi));
  return r;
}

// ---------------- merged prep (1 launch) ----------------
__global__ void k_prep(const float* __restrict__ x, u16* __restrict__ x_bf,
    const float* __restrict__ w1ih, const float* __restrict__ w1hh,
    const float* __restrict__ b1ih, const float* __restrict__ b1hh,
    u16* __restrict__ Wc1, float* __restrict__ bs1,
    const float* __restrict__ w2ih, const float* __restrict__ w2hh,
    const float* __restrict__ b2ih, const float* __restrict__ b2hh,
    u16* __restrict__ Wc2, float* __restrict__ bs2,
    const float* __restrict__ w1l, const float* __restrict__ w1r, u16* __restrict__ Wl1,
    const float* __restrict__ w2l, const float* __restrict__ w2r, u16* __restrict__ Wl2) {
  const int bid = blockIdx.x, tid = threadIdx.x;
  { // x -> bf16
    int i = bid * 256 + tid;
    const float* pp = x + (size_t)i * 8;
    u16x8 o;
    #pragma unroll
    for (int j = 0; j < 8; ++j) o[j] = f2bf(pp[j]);
    *(u16x8*)(x_bf + (size_t)i * 8) = o;
  }
  if (bid < 1024) {            // LSTM weight packs (pre-scaled by log2e / 2log2e)
    const int b2 = bid >= 512;
    const float* wih = b2 ? w2ih : w1ih;
    const float* whh = b2 ? w2hh : w1hh;
    const float* bih = b2 ? b2ih : b1ih;
    const float* bhh = b2 ? b2hh : b1hh;
    u16* Wc = b2 ? Wc2 : Wc1;
    float* bsp = b2 ? bs2 : bs1;
    int idx = (bid & 511) * 256 + tid;
    int g = idx >> 8, k = idx & 255;
    float sc = ((g >> 7) == 2) ? L2E2 : L2E;
    float v = (k < CH) ? wih[g * CH + k] : whh[g * CH + (k - CH)];
    Wc[g * 256 + k] = f2bf(v * sc);
    if (k == 0) bsp[g] = (bih[g] + bhh[g]) * sc;
  } else if (bid < 1280) {     // linear packs
    const int b2 = bid >= 1152;
    const float* wl = b2 ? w2l : w1l;
    const float* wr = b2 ? w2r : w1r;
    u16* W = b2 ? Wl2 : Wl1;
    int idx = ((bid - 1024) & 127) * 256 + tid;
    int o = idx >> 8, k = idx & 255;
    float v = (k < CH) ? wl[o * CH + k] : wr[o * CH + (k - CH)];
    W[o * 256 + k] = f2bf(v);
  }
}

// full fused K=256 chain: ACC0/ACC1 for this role's 2 gates, tile MT
#define MM8(ACC0, ACC1, RD, MT) do {                                           \
  const char* ap_ = ldsc + (RD) + (MT) * 8192;                                 \
  bf16x8 A_;                                                                   \
  A_ = *(const bf16x8*)(ap_ + aE);                                             \
  ACC0 = __builtin_amdgcn_mfma_f32_16x16x32_bf16(A_, Wf[0][0], bias[0],0,0,0); \
  ACC1 = __builtin_amdgcn_mfma_f32_16x16x32_bf16(A_, Wf[1][0], bias[1],0,0,0); \
  A_ = *(const bf16x8*)(ap_ + aO);                                             \
  ACC0 = __builtin_amdgcn_mfma_f32_16x16x32_bf16(A_, Wf[0][1], ACC0, 0,0,0);   \
  ACC1 = __builtin_amdgcn_mfma_f32_16x16x32_bf16(A_, Wf[1][1], ACC1, 0,0,0);   \
  A_ = *(const bf16x8*)(ap_ + aE + 128);                                       \
  ACC0 = __builtin_amdgcn_mfma_f32_16x16x32_bf16(A_, Wf[0][2], ACC0, 0,0,0);   \
  ACC1 = __builtin_amdgcn_mfma_f32_16x16x32_bf16(A_, Wf[1][2], ACC1, 0,0,0);   \
  A_ = *(const bf16x8*)(ap_ + aO + 128);                                       \
  ACC0 = __builtin_amdgcn_mfma_f32_16x16x32_bf16(A_, Wf[0][3], ACC0, 0,0,0);   \
  ACC1 = __builtin_amdgcn_mfma_f32_16x16x32_bf16(A_, Wf[1][3], ACC1, 0,0,0);   \
  A_ = *(const bf16x8*)(ap_ + aE + 256);                                       \
  ACC0 = __builtin_amdgcn_mfma_f32_16x16x32_bf16(A_, Wf[0][4], ACC0, 0,0,0);   \
  ACC1 = __builtin_amdgcn_mfma_f32_16x16x32_bf16(A_, Wf[1][4], ACC1, 0,0,0);   \
  A_ = *(const bf16x8*)(ap_ + aO + 256);                                       \
  ACC0 = __builtin_amdgcn_mfma_f32_16x16x32_bf16(A_, Wf[0][5], ACC0, 0,0,0);   \
  ACC1 = __builtin_amdgcn_mfma_f32_16x16x32_bf16(A_, Wf[1][5], ACC1, 0,0,0);   \
  A_ = *(const bf16x8*)(ap_ + aE + 384);                                       \
  ACC0 = __builtin_amdgcn_mfma_f32_16x16x32_bf16(A_, Wf[0][6], ACC0, 0,0,0);   \
  ACC1 = __builtin_amdgcn_mfma_f32_16x16x32_bf16(A_, Wf[1][6], ACC1, 0,0,0);   \
  A_ = *(const bf16x8*)(ap_ + aO + 384);                                       \
  ACC0 = __builtin_amdgcn_mfma_f32_16x16x32_bf16(A_, Wf[0][7], ACC0, 0,0,0);   \
  ACC1 = __builtin_amdgcn_mfma_f32_16x16x32_bf16(A_, Wf[1][7], ACC1, 0,0,0);   \
} while (0)

// A-role cell for tile MT (AI = gate-i acc, AF = gate-f acc)
#define CELLMT(MT, AI, AF) do {                                                \
  uint4 TG_ = *(const uint4*)(ldsc + exa + (MT) * 2048);                       \
  uint4 SO_ = *(const uint4*)(ldsc + exa + (MT) * 2048 + 1024);                \
  float tg4[4] = { __uint_as_float(TG_.x), __uint_as_float(TG_.y),             \
                   __uint_as_float(TG_.z), __uint_as_float(TG_.w) };           \
  float so4[4] = { __uint_as_float(SO_.x), __uint_as_float(SO_.y),             \
                   __uint_as_float(SO_.z), __uint_as_float(SO_.w) };           \
  float hq[4];                                                                 \
  _Pragma("unroll")                                                            \
  for (int q = 0; q < 4; ++q) {                                                \
    float si = rcpf_fast(1.0f + exp2f_fast(-AI[q]));                           \
    float sf = rcpf_fast(1.0f + exp2f_fast(-AF[q]));                           \
    float c  = fmaf(sf, cst[MT][q], si * tg4[q]);                              \
    cst[MT][q] = c;                                                            \
    float tc = fmaf(-2.0f, rcpf_fast(1.0f + exp2f_fast(c * L2E2)), 1.0f);      \
    hq[q] = so4[q] * tc;                                                       \
  }                                                                            \
  u32 hp0 = cvtpk(hq[0], hq[1]);                                               \
  u32 hp1 = cvtpk(hq[2], hq[3]);                                               \
  if (t != DEG - 1) {                                                          \
    *(u16*)(ldsc + (hw ^  0) + (MT) * 8192 +    0) = (u16)hp0;                 \
    *(u16*)(ldsc + (hw ^ 16) + (MT) * 8192 +  512) = (u16)(hp0 >> 16);         \
    *(u16*)(ldsc + (hw ^ 32) + (MT) * 8192 + 1024) = (u16)hp1;                 \
    *(u16*)(ldsc + (hw ^ 48) + (MT) * 8192 + 1536) = (u16)(hp1 >> 16);         \
  } else {                                                                     \
    u16* op_ = aggrp + (MT) * 16 * CH;                                         \
    op_[0 * CH] = (u16)hp0;                                                    \
    op_[1 * CH] = (u16)(hp0 >> 16);                                            \
    op_[2 * CH] = (u16)hp1;                                                    \
    op_[3 * CH] = (u16)(hp1 >> 16);                                            \
  }                                                                            \
} while (0)

// ---------------- fused LSTM: gate-split, r3 layout, 4 waves/SIMD ----------------
__global__ __launch_bounds__(1024, 4)
void k_lstm(const u16* __restrict__ xin, const int* __restrict__ src,
            const u16* __restrict__ Wc, const float* __restrict__ bs,
            u16* __restrict__ aggr) {
  __shared__ char lds[LDSZ];
  char* ldsc = lds;
  const int tid = threadIdx.x;
  const int lane = tid & 63;
  const int wave = tid >> 6;
  const int g    = wave & 7;       // channel group
  const int role = wave >> 3;      // 0 = A (i,f + cell), 1 = B (g,o + staging)
  const int l15 = lane & 15;
  const int lg  = lane >> 4;
  const int nodeBase = blockIdx.x * MB;

  // srcsT[t][node]
  *(int*)(ldsc + STB + (tid & 15) * 256 + (tid >> 4) * 4) = src[nodeBase * DEG + tid];
  { // zero h region of buf0 (r3's stgH pattern)
    int rr = tid >> 4, cc = (tid & 15) * 16;
    uint4 z{0, 0, 0, 0};
    *(uint4*)(ldsc + rr * 512 + ((256 + cc) ^ ((rr & 7) << 4))) = z;
  }

  // weight frags: rows (role*2+j)*128 + g*16 + l15, full K=256 (pre-scaled)
  bf16x8 Wf[2][8];
  f32x4 bias[2];
  #pragma unroll
  for (int j = 0; j < 2; ++j) {
    const u16* wp = Wc + (size_t)((role * 2 + j) * CH + g * 16 + l15) * 256 + lg * 8;
    #pragma unroll
    for (int kt = 0; kt < 8; ++kt) Wf[j][kt] = *(const bf16x8*)(wp + kt * 32);
    float b = bs[(role * 2 + j) * CH + g * 16 + l15];
    bias[j] = { b, b, b, b };
  }

  // addresses (r3-verified patterns; rows 512B, swizzle byte col ^= (row&7)<<4)
  const int aE = l15 * 512 + ((lg * 16) ^ ((l15 & 7) << 4));
  const int aO = aE ^ 64;
  int hw = lg * 2048 + ((256 + g * 32 + l15 * 2) ^ ((lg & 1) << 6)) + 32768;
  const int exa = EXB + g * 8192 + lane * 16;
  u16* aggrp = aggr + (size_t)(nodeBase + lg * 4) * CH + g * 16 + l15;

  // B staging geometry: 512 B-threads, 8 per row, 32B each
  const int bidx = tid & 511;
  const int brow = bidx >> 3;
  const int bc   = (bidx & 7) * 32;
  const int bswz = (brow & 7) << 4;
  const int sd0 = brow * 512 + (bc ^ bswz);
  const int sd1 = brow * 512 + ((bc + 16) ^ bswz);
  const int goff = (bidx & 7) * 16;     // u16 offset of first 16B chunk

  float cst[4][4] = {{0.f}};
  uint4 xCur0, xCur1, gN0, gN1;
  int rdB = 0;

  __syncthreads();                  // srcsT + zero-h visible

  if (role) {                       // stage x(0) -> buf0; gather x(1) -> xCur
    int s0 = *(const int*)(ldsc + STB + 0 * 256 + brow * 4);
    int s1 = *(const int*)(ldsc + STB + 1 * 256 + brow * 4);
    uint4 a0 = *(const uint4*)(xin + (size_t)(u32)s0 * CH + goff);
    uint4 a1 = *(const uint4*)(xin + (size_t)(u32)s0 * CH + goff + 8);
    *(uint4*)(ldsc + sd0) = a0;
    *(uint4*)(ldsc + sd1) = a1;
    xCur0 = *(const uint4*)(xin + (size_t)(u32)s1 * CH + goff);
    xCur1 = *(const uint4*)(xin + (size_t)(u32)s1 * CH + goff + 8);
  }
  __syncthreads();                  // buf0 = [x(0) | h(-1)=0]

  #pragma unroll 1
  for (int t = 0; t < DEG; ++t) {
    f32x4 ac0a, ac1a, ac0b, ac1b;
    // ---- slot 1 ----
    if (role) {
      if (t < 14) {                 // issue gather x(t+2) (consumed next step)
        int sn = *(const int*)(ldsc + STB + (t + 2) * 256 + brow * 4);
        gN0 = *(const uint4*)(xin + (size_t)(u32)sn * CH + goff);
        gN1 = *(const uint4*)(xin + (size_t)(u32)sn * CH + goff + 8);
      }
      // B: all 4 mt: MFMA (gates g,o) -> tg/so -> exch
      #pragma unroll
      for (int mt = 0; mt < 4; ++mt) {
        MM8(ac0a, ac1a, rdB, mt);
        float tg[4], so[4];
        #pragma unroll
        for (int q = 0; q < 4; ++q) {
          tg[q] = fmaf(-2.0f, rcpf_fast(1.0f + exp2f_fast(ac0a[q])), 1.0f);
          so[q] = rcpf_fast(1.0f + exp2f_fast(-ac1a[q]));
        }
        uint4 TG = { __float_as_uint(tg[0]), __float_as_uint(tg[1]),
                     __float_as_uint(tg[2]), __float_as_uint(tg[3]) };
        uint4 SO = { __float_as_uint(so[0]), __float_as_uint(so[1]),
                     __float_as_uint(so[2]), __float_as_uint(so[3]) };
        *(uint4*)(ldsc + exa + mt * 2048)        = TG;
        *(uint4*)(ldsc + exa + mt * 2048 + 1024) = SO;
      }
    } else {
      // A: MFMA mt0, mt1 (gates i,f)
      MM8(ac0a, ac1a, rdB, 0);
      MM8(ac0b, ac1b, rdB, 1);
    }
    __syncthreads();                // exch ready; rd reads done for A mt01/B all
    // ---- slot 2 ----
    if (role) {
      if (t < 15) {                 // stage x(t+1) into the write buffer
        *(uint4*)(ldsc + (rdB ^ 32768) + sd0) = xCur0;
        *(uint4*)(ldsc + (rdB ^ 32768) + sd1) = xCur1;
      }
      if (t < 14) { xCur0 = gN0; xCur1 = gN1; }
    } else {
      CELLMT(0, ac0a, ac1a);
      CELLMT(1, ac0b, ac1b);
      MM8(ac0a, ac1a, rdB, 2);
      MM8(ac0b, ac1b, rdB, 3);
      CELLMT(2, ac0a, ac1a);
      CELLMT(3, ac0b, ac1b);
    }
    rdB ^= 32768; hw ^= 32768;
    __syncthreads();                // h(t) + x(t+1) staged; buffers swapped
  }
}

// ---------------- fused lin_l/lin_r ----------------
__global__ __launch_bounds__(256, 4)
void k_linear(const u16* __restrict__ aggr, const u16* __restrict__ xroot,
              const u16* __restrict__ W, const float* __restrict__ bl,
              u16* __restrict__ out_bf, float* __restrict__ out_f, int relu) {
  const int lane = threadIdx.x & 63;
  const int wave = threadIdx.x >> 6;
  const int l15 = lane & 15, lg = lane >> 4;
  const int rowBase = blockIdx.x * 64 + wave * 16;

  f32x4 acc[8];
  #pragma unroll
  for (int nt = 0; nt < 8; ++nt) {
    float b = bl[nt * 16 + l15];
    acc[nt] = { b, b, b, b };
  }
  #pragma unroll
  for (int kt = 0; kt < 8; ++kt) {
    const u16* ap = (kt < 4) ? (aggr  + (size_t)(rowBase + l15) * CH + kt * 32 + lg * 8)
                             : (xroot + (size_t)(rowBase + l15) * CH + (kt - 4) * 32 + lg * 8);
    bf16x8 A = *(const bf16x8*)ap;
    #pragma unroll
    for (int nt = 0; nt < 8; ++nt) {
      bf16x8 B = *(const bf16x8*)(W + (nt * 16 + l15) * 256 + kt * 32 + lg * 8);
      acc[nt] = __builtin_amdgcn_mfma_f32_16x16x32_bf16(A, B, acc[nt], 0, 0, 0);
    }
  }
  #pragma unroll
  for (int nt = 0; nt < 8; ++nt) {
    #pragma unroll
    for (int q = 0; q < 4; ++q) {
      float v = acc[nt][q];
      if (relu) v = fmaxf(v, 0.0f);
      int row = rowBase + lg * 4 + q;
      int col = nt * 16 + l15;
      if (out_bf) out_bf[(size_t)row * CH + col] = f2bf(v);
      else        out_f[(size_t)row * CH + col]  = v;
    }
  }
}

extern "C" void kernel_launch(void* const* d_in, const int* in_sizes, int n_in,
                              void* d_out, int out_size, void* d_ws, size_t ws_size,
                              hipStream_t stream) {
  (void)in_sizes; (void)n_in; (void)out_size; (void)ws_size;
  const float* x    = (const float*)d_in[0];
  const int*   ei   = (const int*)d_in[1];
  const float* w1ih = (const float*)d_in[2];
  const float* w1hh = (const float*)d_in[3];
  const float* b1ih = (const float*)d_in[4];
  const float* b1hh = (const float*)d_in[5];
  const float* w1l  = (const float*)d_in[6];
  const float* b1l  = (const float*)d_in[7];
  const float* w1r  = (const float*)d_in[8];
  const float* w2ih = (const float*)d_in[9];
  const float* w2hh = (const float*)d_in[10];
  const float* b2ih = (const float*)d_in[11];
  const float* b2hh = (const float*)d_in[12];
  const float* w2l  = (const float*)d_in[13];
  const float* b2l  = (const float*)d_in[14];
  const float* w2r  = (const float*)d_in[15];

  char* p = (char*)d_ws;
  u16* x_bf  = (u16*)p;  p += (size_t)NN * CH * 2;
  u16* h1_bf = (u16*)p;  p += (size_t)NN * CH * 2;
  u16* ag_bf = (u16*)p;  p += (size_t)NN * CH * 2;
  u16* Wc1   = (u16*)p;  p += (size_t)512 * 256 * 2;
  u16* Wc2   = (u16*)p;  p += (size_t)512 * 256 * 2;
  u16* Wl1   = (u16*)p;  p += (size_t)CH * 256 * 2;
  u16* Wl2   = (u16*)p;  p += (size_t)CH * 256 * 2;
  float* bs1 = (float*)p; p += 512 * 4;
  float* bs2 = (float*)p; p += 512 * 4;

  k_prep<<<2048, 256, 0, stream>>>(x, x_bf,
      w1ih, w1hh, b1ih, b1hh, Wc1, bs1,
      w2ih, w2hh, b2ih, b2hh, Wc2, bs2,
      w1l, w1r, Wl1, w2l, w2r, Wl2);

  k_lstm<<<NN / MB, 1024, 0, stream>>>(x_bf, ei, Wc1, bs1, ag_bf);
  k_linear<<<NN / 64, 256, 0, stream>>>(ag_bf, x_bf, Wl1, b1l, h1_bf, nullptr, 1);
  k_lstm<<<NN / MB, 1024, 0, stream>>>(h1_bf, ei, Wc2, bs2, ag_bf);
  k_linear<<<NN / 64, 256, 0, stream>>>(ag_bf, h1_bf, Wl2, b2l, nullptr, (float*)d_out, 0);
}